// Round 3
// baseline (1027.940 us; speedup 1.0000x reference)
//
#include <hip/hip_runtime.h>

#define NAG 12
#define NTH 4096
#define NEDGE 132
#define LDN 68   // node-buffer row stride (floats)

typedef __bf16 bf16_8 __attribute__((ext_vector_type(8)));
typedef float  f32x4  __attribute__((ext_vector_type(4)));

#define MFMA(a,b,c) __builtin_amdgcn_mfma_f32_16x16x32_bf16((a),(b),(c),0,0,0)

__device__ __forceinline__ float silu_f(float z) {
    float e = __expf(-z);
    return z * __builtin_amdgcn_rcpf(1.0f + e);
}

// B-frag: lane holds B[k=ks*32+quad*8+j][n], W row-major [K][64] fp32 (verified R2)
__device__ __forceinline__ bf16_8 loadB64(const float* __restrict__ W, int kbase, int n) {
    bf16_8 b;
    #pragma unroll
    for (int j = 0; j < 8; ++j) b[j] = (__bf16)W[(kbase + j) * 64 + n];
    return b;
}

// A-frag from 8 consecutive fp32 (16B-aligned)
__device__ __forceinline__ bf16_8 packA8(const float* S) {
    f32x4 u = *(const f32x4*)S, v = *(const f32x4*)(S + 4);
    bf16_8 a;
    a[0]=(__bf16)u.x; a[1]=(__bf16)u.y; a[2]=(__bf16)u.z; a[3]=(__bf16)u.w;
    a[4]=(__bf16)v.x; a[5]=(__bf16)v.y; a[6]=(__bf16)v.z; a[7]=(__bf16)v.w;
    return a;
}

__global__ __launch_bounds__(256, 4) void egnn3(
    const float* __restrict__ h0, const float* __restrict__ x0,
    const float* __restrict__ W_embed, const float* __restrict__ b_embed,
    const float* __restrict__ We1, const float* __restrict__ be1,
    const float* __restrict__ We2, const float* __restrict__ be2,
    const float* __restrict__ Wx, const float* __restrict__ bx,
    const float* __restrict__ Wh1, const float* __restrict__ bh1,
    const float* __restrict__ Wh2, const float* __restrict__ bh2,
    const float* __restrict__ w_act, const float* __restrict__ log_std,
    float* __restrict__ out)
{
    // 19520 B total -> LDS allows 8 blocks/CU; VGPR cap (128) gives 4
    __shared__ __align__(16) float sh_ [NAG * LDN];  // h residual
    __shared__ __align__(16) float sHa_[NAG * LDN];  // h@We1[0:64]; later t1
    __shared__ __align__(16) float sHb_[NAG * LDN];  // h@We1[64:128]
    __shared__ __align__(16) float sAg_[NAG * LDN];  // agg (atomic fp32)
    __shared__ __align__(16) float sx[NAG][16];      // coords [i][d*4+v]
    __shared__ __align__(16) float sRad[144 * 4];
    __shared__ __align__(16) float sWc [NEDGE * 4];
    __shared__ __align__(16) float sWb [5 * 64];     // We1 radial rows (4) + be1

    const int tid  = threadIdx.x;
    const int lane = tid & 63;
    const int g    = tid >> 6;
    const int q    = lane >> 4;
    const int n16  = lane & 15;
    const int col  = g * 16 + n16;
    const int rowA = (n16 < NAG) ? n16 : (NAG - 1);
    const int env  = blockIdx.x;
    const int n0   = env * NAG;

    for (int t = tid; t < NAG * 12; t += 256) sx[t / 12][t % 12] = x0[env * NAG * 12 + t];

    // ---- embed: h = h0 @ W_embed + b ----
    {
        bf16_8 a = packA8(h0 + (n0 + rowA) * 32 + q * 8);
        bf16_8 b = loadB64(W_embed, q * 8, col);
        f32x4 acc = {0.f,0.f,0.f,0.f};
        acc = MFMA(a, b, acc);
        float bias = b_embed[col];
        #pragma unroll
        for (int r = 0; r < 4; ++r) { int rr = q*4+r; if (rr < NAG) sh_[rr*LDN + col] = acc[r] + bias; }
    }
    __syncthreads();   // B0

    for (int l = 0; l < 2; ++l) {
        const float* We1l = We1 + l * NEDGE * 64;
        const float* be1l = be1 + l * 64;
        const float* We2l = We2 + l * 64 * 64;
        const float* be2l = be2 + l * 64;
        const float* Wxl  = Wx  + l * 64 * 4;
        const float* bxl  = bx  + l * 4;
        const float* Wh1l = Wh1 + l * 128 * 64;
        const float* bh1l = bh1 + l * 64;
        const float* Wh2l = Wh2 + l * 64 * 64;
        const float* bh2l = bh2 + l * 64;

        // ======== Stage P: Ha/Hb MFMA, radial, stage We1c+be1, init sWc/sAgg ========
        {
            bf16_8 a0 = packA8(sh_ + rowA * LDN + q * 8);
            bf16_8 a1 = packA8(sh_ + rowA * LDN + 32 + q * 8);
            bf16_8 b0 = loadB64(We1l,           q * 8, col);
            bf16_8 b1 = loadB64(We1l,      32 + q * 8, col);
            bf16_8 c0 = loadB64(We1l + 64*64,   q * 8, col);
            bf16_8 c1 = loadB64(We1l + 64*64, 32 + q * 8, col);
            f32x4 aA = {0.f,0.f,0.f,0.f}, aB = {0.f,0.f,0.f,0.f};
            aA = MFMA(a0, b0, aA); aA = MFMA(a1, b1, aA);
            aB = MFMA(a0, c0, aB); aB = MFMA(a1, c1, aB);
            #pragma unroll
            for (int r = 0; r < 4; ++r) {
                int rr = q*4+r;
                if (rr < NAG) { sHa_[rr*LDN + col] = aA[r]; sHb_[rr*LDN + col] = aB[r]; }
            }
        }
        for (int t = tid; t < 144 * 4; t += 256) {
            int e = t >> 2, v = t & 3; float r = 0.f;
            if (e < NEDGE) {
                int i = e / 11, jj = e - i * 11; int j = jj + (jj >= i);
                #pragma unroll
                for (int d = 0; d < 3; ++d) { float df = sx[i][d*4+v] - sx[j][d*4+v]; r += df*df; }
            }
            sRad[t] = r;
        }
        for (int t = tid; t < 320; t += 256) sWb[t] = (t < 256) ? We1l[128*64 + t] : be1l[t - 256];
        for (int t = tid; t < NEDGE * 4; t += 256) sWc[t] = bxl[t & 3];
        for (int t = tid; t < NAG * 64; t += 256) sAg_[(t >> 6) * LDN + (t & 63)] = 0.f;
        __syncthreads();   // B1

        // ======== Stage E: edge GEMM, M-split; wc in-register; agg via LDS atomics ========
        {
            int eR[3], iI[3], jI[3];
            #pragma unroll
            for (int mtl = 0; mtl < 3; ++mtl) {
                int e = (2*g + mtl) * 16 + n16;
                eR[mtl] = e;
                int ec = e < NEDGE ? e : NEDGE - 1;
                int i = ec / 11, jj = ec - i * 11;
                iI[mtl] = i; jI[mtl] = jj + (jj >= i);
            }
            // s1 A-frags built directly in A-layout (fuses old S2)
            bf16_8 af[3][2];
            #pragma unroll
            for (int kh = 0; kh < 2; ++kh) {
                const int cb = kh * 32 + q * 8;
                f32x4 w0a = *(const f32x4*)(sWb + cb),       w0b = *(const f32x4*)(sWb + cb + 4);
                f32x4 w1a = *(const f32x4*)(sWb + 64 + cb),  w1b = *(const f32x4*)(sWb + 64 + cb + 4);
                f32x4 w2a = *(const f32x4*)(sWb + 128 + cb), w2b = *(const f32x4*)(sWb + 128 + cb + 4);
                f32x4 w3a = *(const f32x4*)(sWb + 192 + cb), w3b = *(const f32x4*)(sWb + 192 + cb + 4);
                f32x4 bea = *(const f32x4*)(sWb + 256 + cb), beb = *(const f32x4*)(sWb + 256 + cb + 4);
                #pragma unroll
                for (int mtl = 0; mtl < 3; ++mtl) {
                    if (mtl == 2 && g != 3) continue;   // wave-uniform
                    const float* pH = sHa_ + iI[mtl] * LDN + cb;
                    const float* pG = sHb_ + jI[mtl] * LDN + cb;
                    f32x4 ha = *(const f32x4*)pH, hb = *(const f32x4*)(pH + 4);
                    f32x4 ga = *(const f32x4*)pG, gb = *(const f32x4*)(pG + 4);
                    f32x4 rd = *(const f32x4*)(sRad + eR[mtl] * 4);
                    f32x4 za = ha + ga + bea + w0a*rd.x + w1a*rd.y + w2a*rd.z + w3a*rd.w;
                    f32x4 zb = hb + gb + beb + w0b*rd.x + w1b*rd.y + w2b*rd.z + w3b*rd.w;
                    bf16_8 a;
                    a[0]=(__bf16)silu_f(za.x); a[1]=(__bf16)silu_f(za.y);
                    a[2]=(__bf16)silu_f(za.z); a[3]=(__bf16)silu_f(za.w);
                    a[4]=(__bf16)silu_f(zb.x); a[5]=(__bf16)silu_f(zb.y);
                    a[6]=(__bf16)silu_f(zb.z); a[7]=(__bf16)silu_f(zb.w);
                    af[mtl][kh] = a;
                }
            }
            f32x4 wca[3][4];
            #pragma unroll
            for (int m2 = 0; m2 < 3; ++m2)
                #pragma unroll
                for (int r = 0; r < 4; ++r) wca[m2][r] = (f32x4){0.f,0.f,0.f,0.f};

            #pragma unroll
            for (int nt = 0; nt < 4; ++nt) {
                bf16_8 b0 = loadB64(We2l,      q * 8, nt*16 + n16);
                bf16_8 b1 = loadB64(We2l, 32 + q * 8, nt*16 + n16);
                f32x4 wx = *(const f32x4*)(Wxl + (nt*16 + n16) * 4);
                float b2 = be2l[nt*16 + n16];
                #pragma unroll
                for (int mtl = 0; mtl < 3; ++mtl) {
                    if (mtl == 2 && g != 3) continue;
                    f32x4 acc = {0.f,0.f,0.f,0.f};
                    acc = MFMA(af[mtl][0], b0, acc);
                    acc = MFMA(af[mtl][1], b1, acc);
                    #pragma unroll
                    for (int r = 0; r < 4; ++r) {
                        float mv = silu_f(acc[r] + b2);
                        int rw = (2*g + mtl) * 16 + q*4 + r;
                        if (rw < NEDGE) atomicAdd(&sAg_[(rw/11) * LDN + nt*16 + n16], mv);
                        wca[mtl][r] += wx * mv;
                    }
                }
            }
            // wc: 16-lane butterfly (sum over all 64 cols, held by this wave) + write
            #pragma unroll
            for (int mtl = 0; mtl < 3; ++mtl) {
                if (mtl == 2 && g != 3) continue;
                #pragma unroll
                for (int r = 0; r < 4; ++r) {
                    f32x4 w = wca[mtl][r];
                    #pragma unroll
                    for (int s = 1; s < 16; s <<= 1) {
                        w.x += __shfl_xor(w.x, s);
                        w.y += __shfl_xor(w.y, s);
                        w.z += __shfl_xor(w.z, s);
                        w.w += __shfl_xor(w.w, s);
                    }
                    int rw = (2*g + mtl) * 16 + q*4 + r;
                    if (n16 < 4 && rw < NEDGE) {
                        float val = (n16 & 1) ? ((n16 & 2) ? w.w : w.y)
                                              : ((n16 & 2) ? w.z : w.x);
                        sWc[rw * 4 + n16] += val;   // exclusive owner; bias pre-loaded
                    }
                }
            }
        }
        __syncthreads();   // B2

        // ======== Stage N: xacc (read-only on sx) + t1 = silu([h,agg]@Wh1+b) ========
        const int xi = tid >> 4, dv = tid & 15;
        const bool act = (xi < NAG) && (dv < 12);
        float xacc = 0.f;
        if (act) {
            const int v = dv & 3;
            float xiv = sx[xi][dv];
            #pragma unroll
            for (int j = 0; j < NAG; ++j) {
                if (j == xi) continue;
                int e = xi * 11 + j - (j > xi);
                xacc += (xiv - sx[j][dv]) * sWc[e * 4 + v];
            }
        }
        {
            bf16_8 a0 = packA8(sh_  + rowA * LDN + q * 8);
            bf16_8 a1 = packA8(sh_  + rowA * LDN + 32 + q * 8);
            bf16_8 a2 = packA8(sAg_ + rowA * LDN + q * 8);
            bf16_8 a3 = packA8(sAg_ + rowA * LDN + 32 + q * 8);
            bf16_8 b0 = loadB64(Wh1l,             q * 8, col);
            bf16_8 b1 = loadB64(Wh1l,        32 + q * 8, col);
            bf16_8 b2 = loadB64(Wh1l + 64*64,     q * 8, col);
            bf16_8 b3 = loadB64(Wh1l + 64*64, 32 + q * 8, col);
            f32x4 acc = {0.f,0.f,0.f,0.f};
            acc = MFMA(a0, b0, acc); acc = MFMA(a1, b1, acc);
            acc = MFMA(a2, b2, acc); acc = MFMA(a3, b3, acc);
            float bias = bh1l[col];
            #pragma unroll
            for (int r = 0; r < 4; ++r) { int rr = q*4+r; if (rr < NAG) sHa_[rr*LDN + col] = silu_f(acc[r] + bias); }
        }
        __syncthreads();   // B3

        // ======== Stage F: x += xacc/11 ; h += t1@Wh2 + b ========
        if (act) sx[xi][dv] += xacc * (1.0f / 11.0f);
        {
            bf16_8 a0 = packA8(sHa_ + rowA * LDN + q * 8);
            bf16_8 a1 = packA8(sHa_ + rowA * LDN + 32 + q * 8);
            bf16_8 b0 = loadB64(Wh2l,      q * 8, col);
            bf16_8 b1 = loadB64(Wh2l, 32 + q * 8, col);
            f32x4 acc = {0.f,0.f,0.f,0.f};
            acc = MFMA(a0, b0, acc); acc = MFMA(a1, b1, acc);
            float bias = bh2l[col];
            #pragma unroll
            for (int r = 0; r < 4; ++r) { int rr = q*4+r; if (rr < NAG) sh_[rr*LDN + col] += acc[r] + bias; }
        }
        __syncthreads();   // B4
    }

    // ---- epilogue ----
    if (tid < NAG * 3) {
        const int i = tid / 3, d = tid - i * 3;
        float mu = 0.f;
        #pragma unroll
        for (int v = 0; v < 4; ++v) mu += sx[i][d*4 + v] * w_act[v];
        out[env * (NAG*3) + tid] = mu;
        out[NTH * NAG * 3 + env * (NAG*3) + tid] = -log_std[d] - 0.9189385332046727f;
    }
}

extern "C" void kernel_launch(void* const* d_in, const int* in_sizes, int n_in,
                              void* d_out, int out_size, void* d_ws, size_t ws_size,
                              hipStream_t stream) {
    // inputs: h0,x0,W_embed,b_embed,We1,be1,We2,be2,Wx,bx,Wh1,bh1,Wh2,bh2,w_act,log_std,row,col
    // row/col structurally known (fully-connected 12-agent graphs) -> unused.
    egnn3<<<dim3(NTH), dim3(256), 0, stream>>>(
        (const float*)d_in[0],  (const float*)d_in[1],  (const float*)d_in[2],
        (const float*)d_in[3],  (const float*)d_in[4],  (const float*)d_in[5],
        (const float*)d_in[6],  (const float*)d_in[7],  (const float*)d_in[8],
        (const float*)d_in[9],  (const float*)d_in[10], (const float*)d_in[11],
        (const float*)d_in[12], (const float*)d_in[13], (const float*)d_in[14],
        (const float*)d_in[15], (float*)d_out);
}

// Round 4
// 774.698 us; speedup vs baseline: 1.3269x; 1.3269x over previous
//
#include <hip/hip_runtime.h>

#define NAG 12
#define NTH 4096
#define NEDGE 132
#define LDN 68   // node-buffer row stride (floats)

typedef __bf16 bf16_8 __attribute__((ext_vector_type(8)));
typedef float  f32x4  __attribute__((ext_vector_type(4)));

#define MFMA(a,b,c) __builtin_amdgcn_mfma_f32_16x16x32_bf16((a),(b),(c),0,0,0)

__device__ __forceinline__ float silu_f(float z) {
    float e = __expf(-z);
    return z * __builtin_amdgcn_rcpf(1.0f + e);
}

// B-frag: lane holds B[k=ks*32+quad*8+j][n], W row-major [K][64] fp32 (verified R2)
__device__ __forceinline__ bf16_8 loadB64(const float* __restrict__ W, int kbase, int n) {
    bf16_8 b;
    #pragma unroll
    for (int j = 0; j < 8; ++j) b[j] = (__bf16)W[(kbase + j) * 64 + n];
    return b;
}

// A-frag from 8 consecutive fp32 (16B-aligned)
__device__ __forceinline__ bf16_8 packA8(const float* S) {
    f32x4 u = *(const f32x4*)S, v = *(const f32x4*)(S + 4);
    bf16_8 a;
    a[0]=(__bf16)u.x; a[1]=(__bf16)u.y; a[2]=(__bf16)u.z; a[3]=(__bf16)u.w;
    a[4]=(__bf16)v.x; a[5]=(__bf16)v.y; a[6]=(__bf16)v.z; a[7]=(__bf16)v.w;
    return a;
}

// amdgpu_waves_per_eu(4,4): pin EXACTLY 4 waves/EU -> VGPR budget 128, 4 blocks/CU.
// R3 lesson: a bare minimum (launch_bounds(...,4)) let the backend target the
// LDS-derived 8 waves/EU -> 64 VGPRs -> 2.4 GB of scratch spills.
__global__ void __launch_bounds__(256) __attribute__((amdgpu_waves_per_eu(4, 4))) egnn4(
    const float* __restrict__ h0, const float* __restrict__ x0,
    const float* __restrict__ W_embed, const float* __restrict__ b_embed,
    const float* __restrict__ We1, const float* __restrict__ be1,
    const float* __restrict__ We2, const float* __restrict__ be2,
    const float* __restrict__ Wx, const float* __restrict__ bx,
    const float* __restrict__ Wh1, const float* __restrict__ bh1,
    const float* __restrict__ Wh2, const float* __restrict__ bh2,
    const float* __restrict__ w_act, const float* __restrict__ log_std,
    float* __restrict__ out)
{
    // ~19.3 KB LDS
    __shared__ __align__(16) float sh_ [NAG * LDN];  // h residual
    __shared__ __align__(16) float sHa_[NAG * LDN];  // h@We1[0:64] + be1; later t1
    __shared__ __align__(16) float sHb_[NAG * LDN];  // h@We1[64:128]
    __shared__ __align__(16) float sAg_[NAG * LDN];  // agg (atomic fp32)
    __shared__ __align__(16) float sx[NAG][16];      // coords [i][d*4+v]
    __shared__ __align__(16) float sRad[144 * 4];    // radial, zero-padded to 144 edges
    __shared__ __align__(16) float sWc [NEDGE * 4];  // coord weights (bias-initialized)
    __shared__ __align__(16) float sWb [4 * 64];     // We1 radial rows

    const int tid  = threadIdx.x;
    const int lane = tid & 63;
    const int g    = tid >> 6;
    const int q    = lane >> 4;
    const int n16  = lane & 15;
    const int col  = g * 16 + n16;
    const int rowA = (n16 < NAG) ? n16 : (NAG - 1);
    const int env  = blockIdx.x;
    const int n0   = env * NAG;

    for (int t = tid; t < NAG * 12; t += 256) sx[t / 12][t % 12] = x0[env * NAG * 12 + t];

    // ---- embed: h = h0 @ W_embed + b ----
    {
        bf16_8 a = packA8(h0 + (n0 + rowA) * 32 + q * 8);
        bf16_8 b = loadB64(W_embed, q * 8, col);
        f32x4 acc = {0.f,0.f,0.f,0.f};
        acc = MFMA(a, b, acc);
        float bias = b_embed[col];
        #pragma unroll
        for (int r = 0; r < 4; ++r) { int rr = q*4+r; if (rr < NAG) sh_[rr*LDN + col] = acc[r] + bias; }
    }
    __syncthreads();   // B0

    for (int l = 0; l < 2; ++l) {
        const float* We1l = We1 + l * NEDGE * 64;
        const float* be1l = be1 + l * 64;
        const float* We2l = We2 + l * 64 * 64;
        const float* be2l = be2 + l * 64;
        const float* Wxl  = Wx  + l * 64 * 4;
        const float* bxl  = bx  + l * 4;
        const float* Wh1l = Wh1 + l * 128 * 64;
        const float* bh1l = bh1 + l * 64;
        const float* Wh2l = Wh2 + l * 64 * 64;
        const float* bh2l = bh2 + l * 64;

        // ======== Stage P: Ha(+be1)/Hb MFMA, radial, stage We1c, init sWc/sAgg ========
        {
            bf16_8 a0 = packA8(sh_ + rowA * LDN + q * 8);
            bf16_8 a1 = packA8(sh_ + rowA * LDN + 32 + q * 8);
            bf16_8 b0 = loadB64(We1l,           q * 8, col);
            bf16_8 b1 = loadB64(We1l,      32 + q * 8, col);
            bf16_8 c0 = loadB64(We1l + 64*64,   q * 8, col);
            bf16_8 c1 = loadB64(We1l + 64*64, 32 + q * 8, col);
            f32x4 aA = {0.f,0.f,0.f,0.f}, aB = {0.f,0.f,0.f,0.f};
            aA = MFMA(a0, b0, aA); aA = MFMA(a1, b1, aA);
            aB = MFMA(a0, c0, aB); aB = MFMA(a1, c1, aB);
            float be1v = be1l[col];
            #pragma unroll
            for (int r = 0; r < 4; ++r) {
                int rr = q*4+r;
                if (rr < NAG) { sHa_[rr*LDN + col] = aA[r] + be1v; sHb_[rr*LDN + col] = aB[r]; }
            }
        }
        for (int t = tid; t < 144 * 4; t += 256) {
            int e = t >> 2, v = t & 3; float r = 0.f;
            if (e < NEDGE) {
                int i = e / 11, jj = e - i * 11; int j = jj + (jj >= i);
                #pragma unroll
                for (int d = 0; d < 3; ++d) { float df = sx[i][d*4+v] - sx[j][d*4+v]; r += df*df; }
            }
            sRad[t] = r;
        }
        sWb[tid] = We1l[128*64 + tid];                              // 256 floats
        for (int t = tid; t < NEDGE * 4; t += 256) sWc[t] = bxl[t & 3];
        for (int t = tid; t < NAG * 64; t += 256) sAg_[(t >> 6) * LDN + (t & 63)] = 0.f;
        __syncthreads();   // B1

        // ======== Stage E: edge GEMM, sequential M-tiles (low VGPR pressure) ========
        {
            // We2 B-frags held across tiles (32 VGPRs)
            bf16_8 bfr[4][2];
            #pragma unroll
            for (int nt = 0; nt < 4; ++nt) {
                bfr[nt][0] = loadB64(We2l,      q * 8, nt*16 + n16);
                bfr[nt][1] = loadB64(We2l, 32 + q * 8, nt*16 + n16);
            }
            const int ntiles = (g == 3) ? 3 : 2;   // tiles {0,1},{2,3},{4,5},{6,7,8}
            for (int tt = 0; tt < ntiles; ++tt) {
                const int t = 2*g + tt;
                const int e = t*16 + n16;
                const int ec = (e < NEDGE) ? e : (NEDGE - 1);
                const int i = ec / 11, jj = ec - i * 11;
                const int j = jj + (jj >= i);
                const f32x4 rd = *(const f32x4*)(sRad + e * 4);   // zero-padded past 132
                // s1 A-frags built directly in A-layout (one We1c pair live at a time)
                bf16_8 af0, af1;
                #pragma unroll
                for (int kh = 0; kh < 2; ++kh) {
                    const int cb = kh * 32 + q * 8;
                    f32x4 za = *(const f32x4*)(sHa_ + i*LDN + cb)
                             + *(const f32x4*)(sHb_ + j*LDN + cb);
                    f32x4 zb = *(const f32x4*)(sHa_ + i*LDN + cb + 4)
                             + *(const f32x4*)(sHb_ + j*LDN + cb + 4);
                    #pragma unroll
                    for (int v = 0; v < 4; ++v) {
                        float rv = rd[v];
                        za += rv * *(const f32x4*)(sWb + v*64 + cb);
                        zb += rv * *(const f32x4*)(sWb + v*64 + cb + 4);
                    }
                    bf16_8 a;
                    a[0]=(__bf16)silu_f(za.x); a[1]=(__bf16)silu_f(za.y);
                    a[2]=(__bf16)silu_f(za.z); a[3]=(__bf16)silu_f(za.w);
                    a[4]=(__bf16)silu_f(zb.x); a[5]=(__bf16)silu_f(zb.y);
                    a[6]=(__bf16)silu_f(zb.z); a[7]=(__bf16)silu_f(zb.w);
                    if (kh == 0) af0 = a; else af1 = a;
                }
                f32x4 wca[4];
                #pragma unroll
                for (int r = 0; r < 4; ++r) wca[r] = (f32x4){0.f,0.f,0.f,0.f};
                #pragma unroll
                for (int nt = 0; nt < 4; ++nt) {
                    const int c2 = nt*16 + n16;
                    f32x4 acc = {0.f,0.f,0.f,0.f};
                    acc = MFMA(af0, bfr[nt][0], acc);
                    acc = MFMA(af1, bfr[nt][1], acc);
                    f32x4 wx = *(const f32x4*)(Wxl + c2 * 4);
                    float b2 = be2l[c2];
                    #pragma unroll
                    for (int r = 0; r < 4; ++r) {
                        float mv = silu_f(acc[r] + b2);
                        int rw = t*16 + q*4 + r;
                        if (rw < NEDGE) atomicAdd(&sAg_[(rw/11) * LDN + c2], mv);
                        wca[r] += wx * mv;
                    }
                }
                // wc: reduce over n (16 lanes within quad hold the 4x16 cols) + write
                #pragma unroll
                for (int r = 0; r < 4; ++r) {
                    f32x4 w = wca[r];
                    #pragma unroll
                    for (int s = 1; s < 16; s <<= 1) {
                        w.x += __shfl_xor(w.x, s);
                        w.y += __shfl_xor(w.y, s);
                        w.z += __shfl_xor(w.z, s);
                        w.w += __shfl_xor(w.w, s);
                    }
                    int rw = t*16 + q*4 + r;
                    if (n16 < 4 && rw < NEDGE) {
                        float val = (n16 & 1) ? ((n16 & 2) ? w.w : w.y)
                                              : ((n16 & 2) ? w.z : w.x);
                        sWc[rw * 4 + n16] += val;   // exclusive owner; bias pre-loaded
                    }
                }
            }
        }
        __syncthreads();   // B2

        // ======== Stage N: xacc (read-only on sx) + t1 = silu([h,agg]@Wh1+b) ========
        const int xi = tid >> 4, dv = tid & 15;
        const bool act = (xi < NAG) && (dv < 12);
        float xacc = 0.f;
        if (act) {
            const int v = dv & 3;
            float xiv = sx[xi][dv];
            #pragma unroll
            for (int j = 0; j < NAG; ++j) {
                if (j == xi) continue;
                int e = xi * 11 + j - (j > xi);
                xacc += (xiv - sx[j][dv]) * sWc[e * 4 + v];
            }
        }
        {
            bf16_8 a0 = packA8(sh_  + rowA * LDN + q * 8);
            bf16_8 a1 = packA8(sh_  + rowA * LDN + 32 + q * 8);
            bf16_8 a2 = packA8(sAg_ + rowA * LDN + q * 8);
            bf16_8 a3 = packA8(sAg_ + rowA * LDN + 32 + q * 8);
            bf16_8 b0 = loadB64(Wh1l,             q * 8, col);
            bf16_8 b1 = loadB64(Wh1l,        32 + q * 8, col);
            bf16_8 b2 = loadB64(Wh1l + 64*64,     q * 8, col);
            bf16_8 b3 = loadB64(Wh1l + 64*64, 32 + q * 8, col);
            f32x4 acc = {0.f,0.f,0.f,0.f};
            acc = MFMA(a0, b0, acc); acc = MFMA(a1, b1, acc);
            acc = MFMA(a2, b2, acc); acc = MFMA(a3, b3, acc);
            float bias = bh1l[col];
            #pragma unroll
            for (int r = 0; r < 4; ++r) { int rr = q*4+r; if (rr < NAG) sHa_[rr*LDN + col] = silu_f(acc[r] + bias); }
        }
        __syncthreads();   // B3

        // ======== Stage F: x += xacc/11 ; h += t1@Wh2 + b ========
        if (act) sx[xi][dv] += xacc * (1.0f / 11.0f);
        {
            bf16_8 a0 = packA8(sHa_ + rowA * LDN + q * 8);
            bf16_8 a1 = packA8(sHa_ + rowA * LDN + 32 + q * 8);
            bf16_8 b0 = loadB64(Wh2l,      q * 8, col);
            bf16_8 b1 = loadB64(Wh2l, 32 + q * 8, col);
            f32x4 acc = {0.f,0.f,0.f,0.f};
            acc = MFMA(a0, b0, acc); acc = MFMA(a1, b1, acc);
            float bias = bh2l[col];
            #pragma unroll
            for (int r = 0; r < 4; ++r) { int rr = q*4+r; if (rr < NAG) sh_[rr*LDN + col] += acc[r] + bias; }
        }
        __syncthreads();   // B4
    }

    // ---- epilogue ----
    if (tid < NAG * 3) {
        const int i = tid / 3, d = tid - i * 3;
        float mu = 0.f;
        #pragma unroll
        for (int v = 0; v < 4; ++v) mu += sx[i][d*4 + v] * w_act[v];
        out[env * (NAG*3) + tid] = mu;
        out[NTH * NAG * 3 + env * (NAG*3) + tid] = -log_std[d] - 0.9189385332046727f;
    }
}

extern "C" void kernel_launch(void* const* d_in, const int* in_sizes, int n_in,
                              void* d_out, int out_size, void* d_ws, size_t ws_size,
                              hipStream_t stream) {
    // inputs: h0,x0,W_embed,b_embed,We1,be1,We2,be2,Wx,bx,Wh1,bh1,Wh2,bh2,w_act,log_std,row,col
    // row/col structurally known (fully-connected 12-agent graphs) -> unused.
    egnn4<<<dim3(NTH), dim3(256), 0, stream>>>(
        (const float*)d_in[0],  (const float*)d_in[1],  (const float*)d_in[2],
        (const float*)d_in[3],  (const float*)d_in[4],  (const float*)d_in[5],
        (const float*)d_in[6],  (const float*)d_in[7],  (const float*)d_in[8],
        (const float*)d_in[9],  (const float*)d_in[10], (const float*)d_in[11],
        (const float*)d_in[12], (const float*)d_in[13], (const float*)d_in[14],
        (const float*)d_in[15], (float*)d_out);
}

// Round 5
// 739.195 us; speedup vs baseline: 1.3906x; 1.0480x over previous
//
#include <hip/hip_runtime.h>

#define NAG 12
#define NTH 4096
#define NEDGE 132
#define LDN 68     // node-buffer row stride (floats)
#define NROWS 30   // rows 12..29 are LDS *padding*: total static LDS ~38.9 KB keeps the
                   // compiler's occupancy target at 4 blocks/CU -> VGPR budget 128.
                   // R3/R4 lesson: gfx950 backend budgets VGPRs to the LDS-derived max
                   // occupancy; 19.5 KB LDS -> 8 blocks -> 64 VGPRs -> 1.8 GB spills.
                   // Neither __launch_bounds__(256,4) nor amdgpu_waves_per_eu(4,4)
                   // overrode it. Static LDS size is the lever that works.

typedef __bf16 bf16_8 __attribute__((ext_vector_type(8)));
typedef float  f32x4  __attribute__((ext_vector_type(4)));

#define MFMA(a,b,c) __builtin_amdgcn_mfma_f32_16x16x32_bf16((a),(b),(c),0,0,0)

__device__ __forceinline__ float silu_f(float z) {
    float e = __expf(-z);
    return z * __builtin_amdgcn_rcpf(1.0f + e);
}

// B-frag: lane holds B[k=ks*32+quad*8+j][n], W row-major [K][64] fp32 (verified R2)
__device__ __forceinline__ bf16_8 loadB64(const float* __restrict__ W, int kbase, int n) {
    bf16_8 b;
    #pragma unroll
    for (int j = 0; j < 8; ++j) b[j] = (__bf16)W[(kbase + j) * 64 + n];
    return b;
}

// A-frag from 8 consecutive fp32 (16B-aligned)
__device__ __forceinline__ bf16_8 packA8(const float* S) {
    f32x4 u = *(const f32x4*)S, v = *(const f32x4*)(S + 4);
    bf16_8 a;
    a[0]=(__bf16)u.x; a[1]=(__bf16)u.y; a[2]=(__bf16)u.z; a[3]=(__bf16)u.w;
    a[4]=(__bf16)v.x; a[5]=(__bf16)v.y; a[6]=(__bf16)v.z; a[7]=(__bf16)v.w;
    return a;
}

__global__ void __launch_bounds__(256) egnn5(
    const float* __restrict__ h0, const float* __restrict__ x0,
    const float* __restrict__ W_embed, const float* __restrict__ b_embed,
    const float* __restrict__ We1, const float* __restrict__ be1,
    const float* __restrict__ We2, const float* __restrict__ be2,
    const float* __restrict__ Wx, const float* __restrict__ bx,
    const float* __restrict__ Wh1, const float* __restrict__ bh1,
    const float* __restrict__ Wh2, const float* __restrict__ bh2,
    const float* __restrict__ w_act, const float* __restrict__ log_std,
    float* __restrict__ out)
{
    // 4 x (30*68) + aux = ~38.9 KB -> exactly 4 blocks/CU
    __shared__ __align__(16) float sh_ [NROWS * LDN];  // h residual
    __shared__ __align__(16) float sHa_[NROWS * LDN];  // h@We1[0:64]+be1; later t1
    __shared__ __align__(16) float sHb_[NROWS * LDN];  // h@We1[64:128]
    __shared__ __align__(16) float sAg_[NROWS * LDN];  // agg (atomic fp32)
    __shared__ __align__(16) float sx[NAG][16];        // coords [i][d*4+v]
    __shared__ __align__(16) float sRad[144 * 4];      // radial, zero-padded to 144 edges
    __shared__ __align__(16) float sWc [NEDGE * 4];    // coord weights (bias-initialized)
    __shared__ __align__(16) float sWb [4 * 64];       // We1 radial rows

    const int tid  = threadIdx.x;
    const int lane = tid & 63;
    const int g    = tid >> 6;
    const int q    = lane >> 4;
    const int n16  = lane & 15;
    const int col  = g * 16 + n16;
    const int rowA = (n16 < NAG) ? n16 : (NAG - 1);
    const int env  = blockIdx.x;
    const int n0   = env * NAG;

    for (int t = tid; t < NAG * 12; t += 256) sx[t / 12][t % 12] = x0[env * NAG * 12 + t];

    // ---- embed: h = h0 @ W_embed + b ----
    {
        bf16_8 a = packA8(h0 + (n0 + rowA) * 32 + q * 8);
        bf16_8 b = loadB64(W_embed, q * 8, col);
        f32x4 acc = {0.f,0.f,0.f,0.f};
        acc = MFMA(a, b, acc);
        float bias = b_embed[col];
        #pragma unroll
        for (int r = 0; r < 4; ++r) { int rr = q*4+r; if (rr < NAG) sh_[rr*LDN + col] = acc[r] + bias; }
    }
    __syncthreads();   // B0

    for (int l = 0; l < 2; ++l) {
        const float* We1l = We1 + l * NEDGE * 64;
        const float* be1l = be1 + l * 64;
        const float* We2l = We2 + l * 64 * 64;
        const float* be2l = be2 + l * 64;
        const float* Wxl  = Wx  + l * 64 * 4;
        const float* bxl  = bx  + l * 4;
        const float* Wh1l = Wh1 + l * 128 * 64;
        const float* bh1l = bh1 + l * 64;
        const float* Wh2l = Wh2 + l * 64 * 64;
        const float* bh2l = bh2 + l * 64;

        // ======== Stage P: Ha(+be1)/Hb MFMA, radial, stage We1c, init sWc/sAgg ========
        {
            bf16_8 a0 = packA8(sh_ + rowA * LDN + q * 8);
            bf16_8 a1 = packA8(sh_ + rowA * LDN + 32 + q * 8);
            bf16_8 b0 = loadB64(We1l,           q * 8, col);
            bf16_8 b1 = loadB64(We1l,      32 + q * 8, col);
            bf16_8 c0 = loadB64(We1l + 64*64,   q * 8, col);
            bf16_8 c1 = loadB64(We1l + 64*64, 32 + q * 8, col);
            f32x4 aA = {0.f,0.f,0.f,0.f}, aB = {0.f,0.f,0.f,0.f};
            aA = MFMA(a0, b0, aA); aA = MFMA(a1, b1, aA);
            aB = MFMA(a0, c0, aB); aB = MFMA(a1, c1, aB);
            float be1v = be1l[col];
            #pragma unroll
            for (int r = 0; r < 4; ++r) {
                int rr = q*4+r;
                if (rr < NAG) { sHa_[rr*LDN + col] = aA[r] + be1v; sHb_[rr*LDN + col] = aB[r]; }
            }
        }
        for (int t = tid; t < 144 * 4; t += 256) {
            int e = t >> 2, v = t & 3; float r = 0.f;
            if (e < NEDGE) {
                int i = e / 11, jj = e - i * 11; int j = jj + (jj >= i);
                #pragma unroll
                for (int d = 0; d < 3; ++d) { float df = sx[i][d*4+v] - sx[j][d*4+v]; r += df*df; }
            }
            sRad[t] = r;
        }
        sWb[tid] = We1l[128*64 + tid];                              // 256 floats
        for (int t = tid; t < NEDGE * 4; t += 256) sWc[t] = bxl[t & 3];
        for (int t = tid; t < NAG * 64; t += 256) sAg_[(t >> 6) * LDN + (t & 63)] = 0.f;
        __syncthreads();   // B1

        // ======== Stage E: edge GEMM, sequential M-tiles (fits 128-VGPR budget) ========
        {
            // We2 B-frags held across tiles (32 VGPRs)
            bf16_8 bfr[4][2];
            #pragma unroll
            for (int nt = 0; nt < 4; ++nt) {
                bfr[nt][0] = loadB64(We2l,      q * 8, nt*16 + n16);
                bfr[nt][1] = loadB64(We2l, 32 + q * 8, nt*16 + n16);
            }
            const int ntiles = (g == 3) ? 3 : 2;   // tiles {0,1},{2,3},{4,5},{6,7,8}
            for (int tt = 0; tt < ntiles; ++tt) {
                const int t = 2*g + tt;
                const int e = t*16 + n16;
                const int ec = (e < NEDGE) ? e : (NEDGE - 1);
                const int i = ec / 11, jj = ec - i * 11;
                const int j = jj + (jj >= i);
                const f32x4 rd = *(const f32x4*)(sRad + e * 4);   // zero-padded past 132
                // s1 A-frags built directly in A-layout (one We1c pair live at a time)
                bf16_8 af0, af1;
                #pragma unroll
                for (int kh = 0; kh < 2; ++kh) {
                    const int cb = kh * 32 + q * 8;
                    f32x4 za = *(const f32x4*)(sHa_ + i*LDN + cb)
                             + *(const f32x4*)(sHb_ + j*LDN + cb);
                    f32x4 zb = *(const f32x4*)(sHa_ + i*LDN + cb + 4)
                             + *(const f32x4*)(sHb_ + j*LDN + cb + 4);
                    #pragma unroll
                    for (int v = 0; v < 4; ++v) {
                        float rv = rd[v];
                        za += rv * *(const f32x4*)(sWb + v*64 + cb);
                        zb += rv * *(const f32x4*)(sWb + v*64 + cb + 4);
                    }
                    bf16_8 a;
                    a[0]=(__bf16)silu_f(za.x); a[1]=(__bf16)silu_f(za.y);
                    a[2]=(__bf16)silu_f(za.z); a[3]=(__bf16)silu_f(za.w);
                    a[4]=(__bf16)silu_f(zb.x); a[5]=(__bf16)silu_f(zb.y);
                    a[6]=(__bf16)silu_f(zb.z); a[7]=(__bf16)silu_f(zb.w);
                    if (kh == 0) af0 = a; else af1 = a;
                }
                f32x4 wca[4];
                #pragma unroll
                for (int r = 0; r < 4; ++r) wca[r] = (f32x4){0.f,0.f,0.f,0.f};
                #pragma unroll
                for (int nt = 0; nt < 4; ++nt) {
                    const int c2 = nt*16 + n16;
                    f32x4 acc = {0.f,0.f,0.f,0.f};
                    acc = MFMA(af0, bfr[nt][0], acc);
                    acc = MFMA(af1, bfr[nt][1], acc);
                    f32x4 wx = *(const f32x4*)(Wxl + c2 * 4);
                    float b2 = be2l[c2];
                    #pragma unroll
                    for (int r = 0; r < 4; ++r) {
                        float mv = silu_f(acc[r] + b2);
                        int rw = t*16 + q*4 + r;
                        if (rw < NEDGE) atomicAdd(&sAg_[(rw/11) * LDN + c2], mv);
                        wca[r] += wx * mv;
                    }
                }
                // wc: reduce over n (16 lanes hold 4x16 cols) + write
                #pragma unroll
                for (int r = 0; r < 4; ++r) {
                    f32x4 w = wca[r];
                    #pragma unroll
                    for (int s = 1; s < 16; s <<= 1) {
                        w.x += __shfl_xor(w.x, s);
                        w.y += __shfl_xor(w.y, s);
                        w.z += __shfl_xor(w.z, s);
                        w.w += __shfl_xor(w.w, s);
                    }
                    int rw = t*16 + q*4 + r;
                    if (n16 < 4 && rw < NEDGE) {
                        float val = (n16 & 1) ? ((n16 & 2) ? w.w : w.y)
                                              : ((n16 & 2) ? w.z : w.x);
                        sWc[rw * 4 + n16] += val;   // exclusive owner; bias pre-loaded
                    }
                }
            }
        }
        __syncthreads();   // B2

        // ======== Stage N: xacc (read-only on sx) + t1 = silu([h,agg]@Wh1+b) ========
        const int xi = tid >> 4, dv = tid & 15;
        const bool act = (xi < NAG) && (dv < 12);
        float xacc = 0.f;
        if (act) {
            const int v = dv & 3;
            float xiv = sx[xi][dv];
            #pragma unroll
            for (int j = 0; j < NAG; ++j) {
                if (j == xi) continue;
                int e = xi * 11 + j - (j > xi);
                xacc += (xiv - sx[j][dv]) * sWc[e * 4 + v];
            }
        }
        {
            bf16_8 a0 = packA8(sh_  + rowA * LDN + q * 8);
            bf16_8 a1 = packA8(sh_  + rowA * LDN + 32 + q * 8);
            bf16_8 a2 = packA8(sAg_ + rowA * LDN + q * 8);
            bf16_8 a3 = packA8(sAg_ + rowA * LDN + 32 + q * 8);
            bf16_8 b0 = loadB64(Wh1l,             q * 8, col);
            bf16_8 b1 = loadB64(Wh1l,        32 + q * 8, col);
            bf16_8 b2 = loadB64(Wh1l + 64*64,     q * 8, col);
            bf16_8 b3 = loadB64(Wh1l + 64*64, 32 + q * 8, col);
            f32x4 acc = {0.f,0.f,0.f,0.f};
            acc = MFMA(a0, b0, acc); acc = MFMA(a1, b1, acc);
            acc = MFMA(a2, b2, acc); acc = MFMA(a3, b3, acc);
            float bias = bh1l[col];
            #pragma unroll
            for (int r = 0; r < 4; ++r) { int rr = q*4+r; if (rr < NAG) sHa_[rr*LDN + col] = silu_f(acc[r] + bias); }
        }
        __syncthreads();   // B3

        // ======== Stage F: x += xacc/11 ; h += t1@Wh2 + b ========
        if (act) sx[xi][dv] += xacc * (1.0f / 11.0f);
        {
            bf16_8 a0 = packA8(sHa_ + rowA * LDN + q * 8);
            bf16_8 a1 = packA8(sHa_ + rowA * LDN + 32 + q * 8);
            bf16_8 b0 = loadB64(Wh2l,      q * 8, col);
            bf16_8 b1 = loadB64(Wh2l, 32 + q * 8, col);
            f32x4 acc = {0.f,0.f,0.f,0.f};
            acc = MFMA(a0, b0, acc); acc = MFMA(a1, b1, acc);
            float bias = bh2l[col];
            #pragma unroll
            for (int r = 0; r < 4; ++r) { int rr = q*4+r; if (rr < NAG) sh_[rr*LDN + col] += acc[r] + bias; }
        }
        __syncthreads();   // B4
    }

    // ---- epilogue ----
    if (tid < NAG * 3) {
        const int i = tid / 3, d = tid - i * 3;
        float mu = 0.f;
        #pragma unroll
        for (int v = 0; v < 4; ++v) mu += sx[i][d*4 + v] * w_act[v];
        out[env * (NAG*3) + tid] = mu;
        out[NTH * NAG * 3 + env * (NAG*3) + tid] = -log_std[d] - 0.9189385332046727f;
    }
}

extern "C" void kernel_launch(void* const* d_in, const int* in_sizes, int n_in,
                              void* d_out, int out_size, void* d_ws, size_t ws_size,
                              hipStream_t stream) {
    // inputs: h0,x0,W_embed,b_embed,We1,be1,We2,be2,Wx,bx,Wh1,bh1,Wh2,bh2,w_act,log_std,row,col
    // row/col structurally known (fully-connected 12-agent graphs) -> unused.
    egnn5<<<dim3(NTH), dim3(256), 0, stream>>>(
        (const float*)d_in[0],  (const float*)d_in[1],  (const float*)d_in[2],
        (const float*)d_in[3],  (const float*)d_in[4],  (const float*)d_in[5],
        (const float*)d_in[6],  (const float*)d_in[7],  (const float*)d_in[8],
        (const float*)d_in[9],  (const float*)d_in[10], (const float*)d_in[11],
        (const float*)d_in[12], (const float*)d_in[13], (const float*)d_in[14],
        (const float*)d_in[15], (float*)d_out);
}

// Round 6
// 251.464 us; speedup vs baseline: 4.0878x; 2.9396x over previous
//
#include <hip/hip_runtime.h>

#define NAG 12
#define NTH 4096
#define NEDGE 132
#define LDB 72    // bf16 row stride: 144 B = 16B-aligned, 36 dwords -> 2-way banks (free)
#define LDA 68    // fp32 agg row stride

typedef __bf16 bf16_8 __attribute__((ext_vector_type(8)));
typedef float  f32x4  __attribute__((ext_vector_type(4)));

#define MFMA(a,b,c) __builtin_amdgcn_mfma_f32_16x16x32_bf16((a),(b),(c),0,0,0)

// ws fragment map (each frag = 64 lanes x 16B = 1024 B = 512 bf16):
//   0..3            : W_embed, nt
//   L = 4 + l*48    : We1a: L+nt*2+kh | We1b: L+8+nt*2+kh | We2: L+16+nt*2+kh
//                     Wh1: L+24+nt*4+ks | Wh2: L+40+nt*2+kh
#define WS_FRAGS 100
#define WS_BYTES (WS_FRAGS * 1024)

__device__ __forceinline__ float silu_f(float z) {
    float e = __expf(-z);
    return z * __builtin_amdgcn_rcpf(1.0f + e);
}

// B-frag from fp32 row-major [K][64]: lane holds B[kbase+q*8+j][n]  (verified R2)
__device__ __forceinline__ bf16_8 loadB64(const float* __restrict__ W, int kbase, int n, int q) {
    bf16_8 b;
    #pragma unroll
    for (int j = 0; j < 8; ++j) b[j] = (__bf16)W[(kbase + q*8 + j) * 64 + n];
    return b;
}

// A-frag from 8 consecutive fp32 (16B-aligned)
__device__ __forceinline__ bf16_8 packA8(const float* S) {
    f32x4 u = *(const f32x4*)S, v = *(const f32x4*)(S + 4);
    bf16_8 a;
    a[0]=(__bf16)u.x; a[1]=(__bf16)u.y; a[2]=(__bf16)u.z; a[3]=(__bf16)u.w;
    a[4]=(__bf16)v.x; a[5]=(__bf16)v.y; a[6]=(__bf16)v.z; a[7]=(__bf16)v.w;
    return a;
}

// ---- prep: pack all weight B-fragments (bf16) into d_ws ----
__global__ __launch_bounds__(64) void prep_frags(
    const float* __restrict__ W_embed, const float* __restrict__ We1,
    const float* __restrict__ We2, const float* __restrict__ Wh1,
    const float* __restrict__ Wh2, __bf16* __restrict__ wsb)
{
    const int f = blockIdx.x, lane = threadIdx.x;
    const int q = lane >> 4, n16 = lane & 15;
    const float* src; int kbase, nbase;
    if (f < 4) { src = W_embed; kbase = 0; nbase = f * 16; }
    else {
        int g0 = f - 4, l = g0 / 48, r = g0 % 48;
        if      (r < 8)  { int nt=r>>1, kh=r&1;            src = We1 + l*NEDGE*64; kbase = kh*32;      nbase = nt*16; }
        else if (r < 16) { int rr=r-8,  nt=rr>>1, kh=rr&1; src = We1 + l*NEDGE*64; kbase = 64 + kh*32; nbase = nt*16; }
        else if (r < 24) { int rr=r-16, nt=rr>>1, kh=rr&1; src = We2 + l*64*64;    kbase = kh*32;      nbase = nt*16; }
        else if (r < 40) { int rr=r-24, nt=rr>>2, ks=rr&3; src = Wh1 + l*128*64;   kbase = ks*32;      nbase = nt*16; }
        else             { int rr=r-40, nt=rr>>1, kh=rr&1; src = Wh2 + l*64*64;    kbase = kh*32;      nbase = nt*16; }
    }
    bf16_8 b = loadB64(src, kbase, nbase + n16, q);
    *(bf16_8*)(wsb + (size_t)f * 512 + lane * 8) = b;
}

template<bool WS>
__device__ __forceinline__ bf16_8 frg(const __bf16* __restrict__ wsb, int fid,
                                      const float* __restrict__ src, int kbase, int n, int lane) {
    if (WS) return *(const bf16_8*)(wsb + (size_t)fid * 512 + lane * 8);
    else    return loadB64(src, kbase, n, (lane >> 4));
}

// ---- main: ONE WAVE PER ENV (64-thread blocks, no cross-wave coupling) ----
template<bool WS>
__global__ __launch_bounds__(64) void egnn6(
    const float* __restrict__ h0, const float* __restrict__ x0,
    const float* __restrict__ W_embed, const float* __restrict__ b_embed,
    const float* __restrict__ We1, const float* __restrict__ be1,
    const float* __restrict__ We2, const float* __restrict__ be2,
    const float* __restrict__ Wx, const float* __restrict__ bx,
    const float* __restrict__ Wh1, const float* __restrict__ bh1,
    const float* __restrict__ Wh2, const float* __restrict__ bh2,
    const float* __restrict__ w_act, const float* __restrict__ log_std,
    const __bf16* __restrict__ wsb, float* __restrict__ out)
{
    // ~16.4 KB -> ~9 blocks/CU; LDS-derived occupancy ~2 waves/SIMD -> VGPR budget >=170
    __shared__ __align__(16) __bf16 sh [NAG * LDB];   // h (bf16 copy; fp32 residual in regs)
    __shared__ __align__(16) __bf16 sHa[NAG * LDB];   // h@We1[0:64]+be1; later t1
    __shared__ __align__(16) __bf16 sHb[NAG * LDB];   // h@We1[64:128]
    __shared__ __align__(16) float  sAg[NAG * LDA];   // agg fp32
    __shared__ __align__(16) __bf16 mst[16 * LDB];    // per-tile m staging
    __shared__ __align__(16) float  sx  [NAG * 16];   // coords [i][d*4+v]
    __shared__ __align__(16) float  sRad[NEDGE * 4];
    __shared__ __align__(16) float  sWc [NEDGE * 4];
    __shared__ __align__(16) float  sWb [4 * 64];     // We1 radial rows (fp32)

    const int lane = threadIdx.x;
    const int q = lane >> 4, n16 = lane & 15;
    const int rowA = (n16 < NAG) ? n16 : (NAG - 1);
    const int env  = blockIdx.x;

    // ---- load x ----
    #pragma unroll
    for (int p = 0; p < 3; ++p) {
        int idx = p * 64 + lane;
        if (idx < NAG * 12) sx[(idx / 12) * 16 + idx % 12] = x0[env * NAG * 12 + idx];
    }

    // ---- embed: h = h0 @ W_embed + b; residual kept in C-frag registers (fp32) ----
    f32x4 hC[4];
    {
        const float* hp = h0 + (env * NAG + rowA) * 32 + q * 8;
        bf16_8 a = packA8(hp);
        #pragma unroll
        for (int nt = 0; nt < 4; ++nt) {
            bf16_8 b = frg<WS>(wsb, nt, W_embed, 0, nt*16 + n16, lane);
            f32x4 acc = {0.f,0.f,0.f,0.f};
            acc = MFMA(a, b, acc);
            float bias = b_embed[nt*16 + n16];
            #pragma unroll
            for (int r = 0; r < 4; ++r) acc[r] += bias;
            hC[nt] = acc;
        }
        #pragma unroll
        for (int nt = 0; nt < 4; ++nt)
            #pragma unroll
            for (int r = 0; r < 4; ++r) {
                int row = q*4 + r;
                if (row < NAG) sh[row*LDB + nt*16 + n16] = (__bf16)hC[nt][r];
            }
    }
    __syncthreads();

    #pragma unroll 1
    for (int l = 0; l < 2; ++l) {
        const float* We1l = We1 + l * NEDGE * 64;
        const float* be1l = be1 + l * 64;
        const float* We2l = We2 + l * 64 * 64;
        const float* be2l = be2 + l * 64;
        const float* Wxl  = Wx  + l * 64 * 4;
        const float* bxl  = bx  + l * 4;
        const float* Wh1l = Wh1 + l * 128 * 64;
        const float* bh1l = bh1 + l * 64;
        const float* Wh2l = Wh2 + l * 64 * 64;
        const float* bh2l = bh2 + l * 64;
        const int L = 4 + l * 48;

        float be1v[4], be2v[4], bh1v[4], bh2v[4];
        #pragma unroll
        for (int nt = 0; nt < 4; ++nt) {
            be1v[nt] = be1l[nt*16+n16]; be2v[nt] = be2l[nt*16+n16];
            bh1v[nt] = bh1l[nt*16+n16]; bh2v[nt] = bh2l[nt*16+n16];
        }
        float bxv = (n16 < 4) ? bxl[n16] : 0.f;

        // ---- Stage A: Ha = h@We1a + be1, Hb = h@We1b (bf16 LDS); radial; We1c stage ----
        {
            bf16_8 a0 = *(const bf16_8*)(sh + rowA*LDB + q*8);
            bf16_8 a1 = *(const bf16_8*)(sh + rowA*LDB + 32 + q*8);
            #pragma unroll
            for (int nt = 0; nt < 4; ++nt) {
                bf16_8 b0 = frg<WS>(wsb, L+nt*2+0,   We1l, 0,  nt*16+n16, lane);
                bf16_8 b1 = frg<WS>(wsb, L+nt*2+1,   We1l, 32, nt*16+n16, lane);
                bf16_8 c0 = frg<WS>(wsb, L+8+nt*2+0, We1l, 64, nt*16+n16, lane);
                bf16_8 c1 = frg<WS>(wsb, L+8+nt*2+1, We1l, 96, nt*16+n16, lane);
                f32x4 aA = {0.f,0.f,0.f,0.f}, aB = {0.f,0.f,0.f,0.f};
                aA = MFMA(a0, b0, aA); aA = MFMA(a1, b1, aA);
                aB = MFMA(a0, c0, aB); aB = MFMA(a1, c1, aB);
                #pragma unroll
                for (int r = 0; r < 4; ++r) {
                    int row = q*4 + r;
                    if (row < NAG) {
                        sHa[row*LDB + nt*16+n16] = (__bf16)(aA[r] + be1v[nt]);
                        sHb[row*LDB + nt*16+n16] = (__bf16)aB[r];
                    }
                }
            }
        }
        #pragma unroll
        for (int p = 0; p < 4; ++p) sWb[p*64 + lane] = We1l[(128+p)*64 + lane];
        #pragma unroll
        for (int p = 0; p < 9; ++p) {
            int idx = p * 64 + lane;
            if (idx < NEDGE * 4) {
                int e = idx >> 2, v = idx & 3;
                int i = e / 11, jj = e - i * 11, j = jj + (jj >= i);
                float r = 0.f;
                #pragma unroll
                for (int d = 0; d < 3; ++d) {
                    float df = sx[i*16 + d*4 + v] - sx[j*16 + d*4 + v];
                    r += df * df;
                }
                sRad[idx] = r;
            }
        }
        __syncthreads();

        // ---- Edge stage: 9 M-tiles, all by this wave; m via per-tile LDS staging ----
        float agg[NAG];
        #pragma unroll
        for (int i = 0; i < NAG; ++i) agg[i] = 0.f;
        bf16_8 w2f[4][2], wxf[2];
        #pragma unroll
        for (int nt = 0; nt < 4; ++nt) {
            w2f[nt][0] = frg<WS>(wsb, L+16+nt*2+0, We2l, 0,  nt*16+n16, lane);
            w2f[nt][1] = frg<WS>(wsb, L+16+nt*2+1, We2l, 32, nt*16+n16, lane);
        }
        #pragma unroll
        for (int kh = 0; kh < 2; ++kh) {   // Wx B-frag, cols 4..15 zero-padded
            bf16_8 b;
            #pragma unroll
            for (int j2 = 0; j2 < 8; ++j2)
                b[j2] = (n16 < 4) ? (__bf16)Wxl[(kh*32 + q*8 + j2)*4 + n16] : (__bf16)0.f;
            wxf[kh] = b;
        }

        #pragma unroll
        for (int t = 0; t < 9; ++t) {
            const int e  = t*16 + n16;
            const int ec = (e < NEDGE) ? e : (NEDGE - 1);
            const int i  = ec / 11;
            const int jj = ec - i * 11;
            const int j  = jj + (jj >= i);
            const f32x4 rd = *(const f32x4*)(sRad + ec * 4);
            // s1 A-frags built directly in A-layout (fused; verified R4/R5 pattern)
            bf16_8 af0, af1;
            #pragma unroll
            for (int kh = 0; kh < 2; ++kh) {
                const int cb = kh*32 + q*8;
                bf16_8 ha = *(const bf16_8*)(sHa + i*LDB + cb);
                bf16_8 hb = *(const bf16_8*)(sHb + j*LDB + cb);
                f32x4 wr0 = {0.f,0.f,0.f,0.f}, wr1 = {0.f,0.f,0.f,0.f};
                #pragma unroll
                for (int v = 0; v < 4; ++v) {
                    f32x4 wa = *(const f32x4*)(sWb + v*64 + cb);        // quad-broadcast
                    f32x4 wb = *(const f32x4*)(sWb + v*64 + cb + 4);
                    wr0 += rd[v] * wa; wr1 += rd[v] * wb;
                }
                bf16_8 a;
                #pragma unroll
                for (int c = 0; c < 4; ++c)
                    a[c]   = (__bf16)silu_f((float)ha[c]   + (float)hb[c]   + wr0[c]);
                #pragma unroll
                for (int c = 0; c < 4; ++c)
                    a[4+c] = (__bf16)silu_f((float)ha[4+c] + (float)hb[4+c] + wr1[c]);
                if (kh == 0) af0 = a; else af1 = a;
            }
            // m = silu(s1@We2 + be2) -> bf16 staging
            #pragma unroll
            for (int nt = 0; nt < 4; ++nt) {
                f32x4 acc = {0.f,0.f,0.f,0.f};
                acc = MFMA(af0, w2f[nt][0], acc);
                acc = MFMA(af1, w2f[nt][1], acc);
                #pragma unroll
                for (int r = 0; r < 4; ++r)
                    mst[(q*4+r)*LDB + nt*16+n16] = (__bf16)silu_f(acc[r] + be2v[nt]);
            }
            __syncthreads();
            // wc = m@Wx + bx via MFMA (N=4 real cols)
            {
                bf16_8 aw0 = *(const bf16_8*)(mst + n16*LDB + q*8);
                bf16_8 aw1 = *(const bf16_8*)(mst + n16*LDB + 32 + q*8);
                f32x4 acc = {0.f,0.f,0.f,0.f};
                acc = MFMA(aw0, wxf[0], acc);
                acc = MFMA(aw1, wxf[1], acc);
                if (n16 < 4) {
                    #pragma unroll
                    for (int r = 0; r < 4; ++r) {
                        int row = t*16 + q*4 + r;
                        if (row < NEDGE) sWc[row*4 + n16] = acc[r] + bxv;
                    }
                }
            }
            // agg: lane = col; node index compile-time via full unroll
            {
                const int elim = (t == 8) ? 4 : 16;
                #pragma unroll
                for (int el = 0; el < 16; ++el) {
                    if (el < elim) {
                        const int node = (t*16 + el) / 11;
                        agg[node] += (float)mst[el*LDB + lane];
                    }
                }
            }
            __syncthreads();   // protect mst before next tile
        }
        #pragma unroll
        for (int i = 0; i < NAG; ++i) sAg[i*LDA + lane] = agg[i];
        __syncthreads();

        // ---- xacc (pre-update x reads) ----
        float xn[3];
        #pragma unroll
        for (int p = 0; p < 3; ++p) {
            int idx = p*64 + lane;
            float res = 0.f;
            if (idx < 144) {
                int xi = idx / 12, dv = idx % 12, v = dv & 3;
                float xiv = sx[xi*16 + dv];
                float acc = 0.f;
                #pragma unroll
                for (int j2 = 0; j2 < NAG; ++j2) {
                    int e = xi*11 + j2 - (j2 > xi ? 1 : 0);
                    e = (e < NEDGE) ? e : (NEDGE - 1);
                    float term = (xiv - sx[j2*16 + dv]) * sWc[e*4 + v];
                    acc += (j2 == xi) ? 0.f : term;
                }
                res = xiv + acc * (1.0f / 11.0f);
            }
            xn[p] = res;
        }
        // ---- Wh1: t1 = silu([h,agg]@Wh1 + bh1) -> sHa (reuse) ----
        {
            bf16_8 ah0 = *(const bf16_8*)(sh + rowA*LDB + q*8);
            bf16_8 ah1 = *(const bf16_8*)(sh + rowA*LDB + 32 + q*8);
            bf16_8 ag0 = packA8(sAg + rowA*LDA + q*8);
            bf16_8 ag1 = packA8(sAg + rowA*LDA + 32 + q*8);
            #pragma unroll
            for (int nt = 0; nt < 4; ++nt) {
                f32x4 acc = {0.f,0.f,0.f,0.f};
                acc = MFMA(ah0, frg<WS>(wsb, L+24+nt*4+0, Wh1l, 0,  nt*16+n16, lane), acc);
                acc = MFMA(ah1, frg<WS>(wsb, L+24+nt*4+1, Wh1l, 32, nt*16+n16, lane), acc);
                acc = MFMA(ag0, frg<WS>(wsb, L+24+nt*4+2, Wh1l, 64, nt*16+n16, lane), acc);
                acc = MFMA(ag1, frg<WS>(wsb, L+24+nt*4+3, Wh1l, 96, nt*16+n16, lane), acc);
                #pragma unroll
                for (int r = 0; r < 4; ++r) {
                    int row = q*4 + r;
                    if (row < NAG) sHa[row*LDB + nt*16+n16] = (__bf16)silu_f(acc[r] + bh1v[nt]);
                }
            }
        }
        __syncthreads();
        // ---- x writeback; Wh2: h += t1@Wh2 + bh2 (register residual) ----
        #pragma unroll
        for (int p = 0; p < 3; ++p) {
            int idx = p*64 + lane;
            if (idx < 144) sx[(idx/12)*16 + idx%12] = xn[p];
        }
        {
            bf16_8 at0 = *(const bf16_8*)(sHa + rowA*LDB + q*8);
            bf16_8 at1 = *(const bf16_8*)(sHa + rowA*LDB + 32 + q*8);
            #pragma unroll
            for (int nt = 0; nt < 4; ++nt) {
                f32x4 acc = {0.f,0.f,0.f,0.f};
                acc = MFMA(at0, frg<WS>(wsb, L+40+nt*2+0, Wh2l, 0,  nt*16+n16, lane), acc);
                acc = MFMA(at1, frg<WS>(wsb, L+40+nt*2+1, Wh2l, 32, nt*16+n16, lane), acc);
                #pragma unroll
                for (int r = 0; r < 4; ++r) hC[nt][r] += acc[r] + bh2v[nt];
            }
            #pragma unroll
            for (int nt = 0; nt < 4; ++nt)
                #pragma unroll
                for (int r = 0; r < 4; ++r) {
                    int row = q*4 + r;
                    if (row < NAG) sh[row*LDB + nt*16+n16] = (__bf16)hC[nt][r];
                }
        }
        __syncthreads();
    }

    // ---- epilogue ----
    if (lane < NAG * 3) {
        int i = lane / 3, d = lane - i * 3;
        float mu = 0.f;
        #pragma unroll
        for (int v = 0; v < 4; ++v) mu += sx[i*16 + d*4 + v] * w_act[v];
        out[env * (NAG*3) + lane] = mu;
        out[NTH * NAG * 3 + env * (NAG*3) + lane] = -log_std[d] - 0.9189385332046727f;
    }
}

extern "C" void kernel_launch(void* const* d_in, const int* in_sizes, int n_in,
                              void* d_out, int out_size, void* d_ws, size_t ws_size,
                              hipStream_t stream) {
    // inputs: h0,x0,W_embed,b_embed,We1,be1,We2,be2,Wx,bx,Wh1,bh1,Wh2,bh2,w_act,log_std,row,col
    const float* h0   = (const float*)d_in[0];
    const float* x0   = (const float*)d_in[1];
    const float* Wem  = (const float*)d_in[2];
    const float* bem  = (const float*)d_in[3];
    const float* We1  = (const float*)d_in[4];
    const float* be1  = (const float*)d_in[5];
    const float* We2  = (const float*)d_in[6];
    const float* be2  = (const float*)d_in[7];
    const float* Wx   = (const float*)d_in[8];
    const float* bx   = (const float*)d_in[9];
    const float* Wh1  = (const float*)d_in[10];
    const float* bh1  = (const float*)d_in[11];
    const float* Wh2  = (const float*)d_in[12];
    const float* bh2  = (const float*)d_in[13];
    const float* wact = (const float*)d_in[14];
    const float* lstd = (const float*)d_in[15];
    float* out = (float*)d_out;

    if (ws_size >= (size_t)WS_BYTES) {
        prep_frags<<<dim3(WS_FRAGS), dim3(64), 0, stream>>>(Wem, We1, We2, Wh1, Wh2, (__bf16*)d_ws);
        egnn6<true><<<dim3(NTH), dim3(64), 0, stream>>>(
            h0, x0, Wem, bem, We1, be1, We2, be2, Wx, bx,
            Wh1, bh1, Wh2, bh2, wact, lstd, (const __bf16*)d_ws, out);
    } else {
        egnn6<false><<<dim3(NTH), dim3(64), 0, stream>>>(
            h0, x0, Wem, bem, We1, be1, We2, be2, Wx, bx,
            Wh1, bh1, Wh2, bh2, wact, lstd, nullptr, out);
    }
}

// Round 7
// 247.889 us; speedup vs baseline: 4.1468x; 1.0144x over previous
//
#include <hip/hip_runtime.h>

#define NAG 12
#define NTH 4096
#define NEDGE 132
#define LDB 72    // bf16 row stride: 144 B = 16B-aligned, 36 dwords -> 2-way banks (free)

typedef __bf16 bf16_8 __attribute__((ext_vector_type(8)));
typedef float  f32x4  __attribute__((ext_vector_type(4)));

#define MFMA(a,b,c) __builtin_amdgcn_mfma_f32_16x16x32_bf16((a),(b),(c),0,0,0)

// ws fragment map (each frag = 64 lanes x 16B = 1024 B = 512 bf16):
//   0..3            : W_embed, nt
//   L = 4 + l*48    : We1a: L+nt*2+kh | We1b: L+8+nt*2+kh | We2: L+16+nt*2+kh
//                     Wh1: L+24+nt*4+ks | Wh2: L+40+nt*2+kh
#define WS_FRAGS 100
#define WS_BYTES (WS_FRAGS * 1024)

__device__ __forceinline__ float silu_f(float z) {
    float e = __expf(-z);
    return z * __builtin_amdgcn_rcpf(1.0f + e);
}

// B-frag from fp32 row-major [K][64]: lane holds B[kbase+q*8+j][n]  (verified R2)
__device__ __forceinline__ bf16_8 loadB64(const float* __restrict__ W, int kbase, int n, int q) {
    bf16_8 b;
    #pragma unroll
    for (int j = 0; j < 8; ++j) b[j] = (__bf16)W[(kbase + q*8 + j) * 64 + n];
    return b;
}

// A-frag from 8 consecutive fp32 (16B-aligned)
__device__ __forceinline__ bf16_8 packA8(const float* S) {
    f32x4 u = *(const f32x4*)S, v = *(const f32x4*)(S + 4);
    bf16_8 a;
    a[0]=(__bf16)u.x; a[1]=(__bf16)u.y; a[2]=(__bf16)u.z; a[3]=(__bf16)u.w;
    a[4]=(__bf16)v.x; a[5]=(__bf16)v.y; a[6]=(__bf16)v.z; a[7]=(__bf16)v.w;
    return a;
}

// ---- prep: pack all weight B-fragments (bf16) into d_ws ----
__global__ __launch_bounds__(64) void prep_frags(
    const float* __restrict__ W_embed, const float* __restrict__ We1,
    const float* __restrict__ We2, const float* __restrict__ Wh1,
    const float* __restrict__ Wh2, __bf16* __restrict__ wsb)
{
    const int f = blockIdx.x, lane = threadIdx.x;
    const int q = lane >> 4, n16 = lane & 15;
    const float* src; int kbase, nbase;
    if (f < 4) { src = W_embed; kbase = 0; nbase = f * 16; }
    else {
        int g0 = f - 4, l = g0 / 48, r = g0 % 48;
        if      (r < 8)  { int nt=r>>1, kh=r&1;            src = We1 + l*NEDGE*64; kbase = kh*32;      nbase = nt*16; }
        else if (r < 16) { int rr=r-8,  nt=rr>>1, kh=rr&1; src = We1 + l*NEDGE*64; kbase = 64 + kh*32; nbase = nt*16; }
        else if (r < 24) { int rr=r-16, nt=rr>>1, kh=rr&1; src = We2 + l*64*64;    kbase = kh*32;      nbase = nt*16; }
        else if (r < 40) { int rr=r-24, nt=rr>>2, ks=rr&3; src = Wh1 + l*128*64;   kbase = ks*32;      nbase = nt*16; }
        else             { int rr=r-40, nt=rr>>1, kh=rr&1; src = Wh2 + l*64*64;    kbase = kh*32;      nbase = nt*16; }
    }
    bf16_8 b = loadB64(src, kbase, nbase + n16, q);
    *(bf16_8*)(wsb + (size_t)f * 512 + lane * 8) = b;
}

template<bool WS>
__device__ __forceinline__ bf16_8 frg(const __bf16* __restrict__ wsb, int fid,
                                      const float* __restrict__ src, int kbase, int n, int lane) {
    if (WS) return *(const bf16_8*)(wsb + (size_t)fid * 512 + lane * 8);
    else    return loadB64(src, kbase, n, (lane >> 4));
}

// ---- main: ONE WAVE PER ENV, ZERO BARRIERS ----
// Block = 1 wave: all __syncthreads removed (DS ops are in-order within a wave;
// compiler inserts lgkmcnt waits on may-aliasing LDS accesses). LDS kept under
// 12.8 KB so the LDS-derived occupancy floor is 3 waves/SIMD -> VGPR budget 170
// (R2/R5/R6 law: the backend budgets VGPRs to the static-LDS occupancy floor).
template<bool WS>
__global__ __launch_bounds__(64) void egnn7(
    const float* __restrict__ h0, const float* __restrict__ x0,
    const float* __restrict__ W_embed, const float* __restrict__ b_embed,
    const float* __restrict__ We1, const float* __restrict__ be1,
    const float* __restrict__ We2, const float* __restrict__ be2,
    const float* __restrict__ Wx, const float* __restrict__ bx,
    const float* __restrict__ Wh1, const float* __restrict__ bh1,
    const float* __restrict__ Wh2, const float* __restrict__ bh2,
    const float* __restrict__ w_act, const float* __restrict__ log_std,
    const __bf16* __restrict__ wsb, float* __restrict__ out)
{
    // 12448 B total
    __shared__ __align__(16) __bf16 sh  [NAG * LDB];   // h (bf16 copy; fp32 residual in regs)
    __shared__ __align__(16) __bf16 sHa [NAG * LDB];   // h@We1[0:64]+be1; later t1
    __shared__ __align__(16) __bf16 sHb [NAG * LDB];   // h@We1[64:128]; later agg (bf16)
    __shared__ __align__(16) __bf16 mst [16 * LDB];    // per-tile m staging
    __shared__ __align__(16) float  sx  [NAG * 16];    // coords [i][d*4+v]
    __shared__ __align__(16) float  sRad[NEDGE * 4];
    __shared__ __align__(16) __bf16 sWcB[NEDGE * 4];   // coord weights (bf16)
    __shared__ __align__(16) float  sWb [4 * 64];      // We1 radial rows (fp32)

    const int lane = threadIdx.x;
    const int q = lane >> 4, n16 = lane & 15;
    const int rowA = (n16 < NAG) ? n16 : (NAG - 1);
    const int env  = blockIdx.x;

    // ---- load x ----
    #pragma unroll
    for (int p = 0; p < 3; ++p) {
        int idx = p * 64 + lane;
        if (idx < NAG * 12) sx[(idx / 12) * 16 + idx % 12] = x0[env * NAG * 12 + idx];
    }

    // ---- embed: h = h0 @ W_embed + b; residual kept in C-frag registers (fp32) ----
    f32x4 hC[4];
    {
        const float* hp = h0 + (env * NAG + rowA) * 32 + q * 8;
        bf16_8 a = packA8(hp);
        #pragma unroll
        for (int nt = 0; nt < 4; ++nt) {
            bf16_8 b = frg<WS>(wsb, nt, W_embed, 0, nt*16 + n16, lane);
            f32x4 acc = {0.f,0.f,0.f,0.f};
            acc = MFMA(a, b, acc);
            float bias = b_embed[nt*16 + n16];
            #pragma unroll
            for (int r = 0; r < 4; ++r) acc[r] += bias;
            hC[nt] = acc;
        }
        #pragma unroll
        for (int nt = 0; nt < 4; ++nt)
            #pragma unroll
            for (int r = 0; r < 4; ++r) {
                int row = q*4 + r;
                if (row < NAG) sh[row*LDB + nt*16 + n16] = (__bf16)hC[nt][r];
            }
    }

    #pragma unroll 1
    for (int l = 0; l < 2; ++l) {
        const float* We1l = We1 + l * NEDGE * 64;
        const float* be1l = be1 + l * 64;
        const float* We2l = We2 + l * 64 * 64;
        const float* be2l = be2 + l * 64;
        const float* Wxl  = Wx  + l * 64 * 4;
        const float* bxl  = bx  + l * 4;
        const float* Wh1l = Wh1 + l * 128 * 64;
        const float* bh1l = bh1 + l * 64;
        const float* Wh2l = Wh2 + l * 64 * 64;
        const float* bh2l = bh2 + l * 64;
        const int L = 4 + l * 48;

        float be1v[4], be2v[4], bh1v[4], bh2v[4];
        #pragma unroll
        for (int nt = 0; nt < 4; ++nt) {
            be1v[nt] = be1l[nt*16+n16]; be2v[nt] = be2l[nt*16+n16];
            bh1v[nt] = bh1l[nt*16+n16]; bh2v[nt] = bh2l[nt*16+n16];
        }
        float bxv = (n16 < 4) ? bxl[n16] : 0.f;

        // ---- Stage A: Ha = h@We1a + be1, Hb = h@We1b (bf16 LDS); radial; We1c stage ----
        {
            bf16_8 a0 = *(const bf16_8*)(sh + rowA*LDB + q*8);
            bf16_8 a1 = *(const bf16_8*)(sh + rowA*LDB + 32 + q*8);
            #pragma unroll
            for (int nt = 0; nt < 4; ++nt) {
                bf16_8 b0 = frg<WS>(wsb, L+nt*2+0,   We1l, 0,  nt*16+n16, lane);
                bf16_8 b1 = frg<WS>(wsb, L+nt*2+1,   We1l, 32, nt*16+n16, lane);
                bf16_8 c0 = frg<WS>(wsb, L+8+nt*2+0, We1l, 64, nt*16+n16, lane);
                bf16_8 c1 = frg<WS>(wsb, L+8+nt*2+1, We1l, 96, nt*16+n16, lane);
                f32x4 aA = {0.f,0.f,0.f,0.f}, aB = {0.f,0.f,0.f,0.f};
                aA = MFMA(a0, b0, aA); aA = MFMA(a1, b1, aA);
                aB = MFMA(a0, c0, aB); aB = MFMA(a1, c1, aB);
                #pragma unroll
                for (int r = 0; r < 4; ++r) {
                    int row = q*4 + r;
                    if (row < NAG) {
                        sHa[row*LDB + nt*16+n16] = (__bf16)(aA[r] + be1v[nt]);
                        sHb[row*LDB + nt*16+n16] = (__bf16)aB[r];
                    }
                }
            }
        }
        #pragma unroll
        for (int p = 0; p < 4; ++p) sWb[p*64 + lane] = We1l[(128+p)*64 + lane];
        #pragma unroll
        for (int p = 0; p < 9; ++p) {
            int idx = p * 64 + lane;
            if (idx < NEDGE * 4) {
                int e = idx >> 2, v = idx & 3;
                int i = e / 11, jj = e - i * 11, j = jj + (jj >= i);
                float r = 0.f;
                #pragma unroll
                for (int d = 0; d < 3; ++d) {
                    float df = sx[i*16 + d*4 + v] - sx[j*16 + d*4 + v];
                    r += df * df;
                }
                sRad[idx] = r;
            }
        }

        // ---- Edge stage: 9 M-tiles; m via per-tile LDS staging (wave-private) ----
        float agg[NAG];
        #pragma unroll
        for (int i = 0; i < NAG; ++i) agg[i] = 0.f;
        bf16_8 w2f[4][2], wxf[2];
        #pragma unroll
        for (int nt = 0; nt < 4; ++nt) {
            w2f[nt][0] = frg<WS>(wsb, L+16+nt*2+0, We2l, 0,  nt*16+n16, lane);
            w2f[nt][1] = frg<WS>(wsb, L+16+nt*2+1, We2l, 32, nt*16+n16, lane);
        }
        #pragma unroll
        for (int kh = 0; kh < 2; ++kh) {   // Wx B-frag, cols 4..15 zero-padded
            bf16_8 b;
            #pragma unroll
            for (int j2 = 0; j2 < 8; ++j2)
                b[j2] = (n16 < 4) ? (__bf16)Wxl[(kh*32 + q*8 + j2)*4 + n16] : (__bf16)0.f;
            wxf[kh] = b;
        }

        #pragma unroll
        for (int t = 0; t < 9; ++t) {
            const int e  = t*16 + n16;
            const int ec = (e < NEDGE) ? e : (NEDGE - 1);
            const int i  = ec / 11;
            const int jj = ec - i * 11;
            const int j  = jj + (jj >= i);
            const f32x4 rd = *(const f32x4*)(sRad + ec * 4);
            // s1 A-frags built directly in A-layout
            bf16_8 af0, af1;
            #pragma unroll
            for (int kh = 0; kh < 2; ++kh) {
                const int cb = kh*32 + q*8;
                bf16_8 ha = *(const bf16_8*)(sHa + i*LDB + cb);
                bf16_8 hb = *(const bf16_8*)(sHb + j*LDB + cb);
                f32x4 wr0 = {0.f,0.f,0.f,0.f}, wr1 = {0.f,0.f,0.f,0.f};
                #pragma unroll
                for (int v = 0; v < 4; ++v) {
                    f32x4 wa = *(const f32x4*)(sWb + v*64 + cb);        // loop-invariant
                    f32x4 wb = *(const f32x4*)(sWb + v*64 + cb + 4);
                    wr0 += rd[v] * wa; wr1 += rd[v] * wb;
                }
                bf16_8 a;
                #pragma unroll
                for (int c = 0; c < 4; ++c)
                    a[c]   = (__bf16)silu_f((float)ha[c]   + (float)hb[c]   + wr0[c]);
                #pragma unroll
                for (int c = 0; c < 4; ++c)
                    a[4+c] = (__bf16)silu_f((float)ha[4+c] + (float)hb[4+c] + wr1[c]);
                if (kh == 0) af0 = a; else af1 = a;
            }
            // m = silu(s1@We2 + be2) -> bf16 staging
            #pragma unroll
            for (int nt = 0; nt < 4; ++nt) {
                f32x4 acc = {0.f,0.f,0.f,0.f};
                acc = MFMA(af0, w2f[nt][0], acc);
                acc = MFMA(af1, w2f[nt][1], acc);
                #pragma unroll
                for (int r = 0; r < 4; ++r)
                    mst[(q*4+r)*LDB + nt*16+n16] = (__bf16)silu_f(acc[r] + be2v[nt]);
            }
            // wc = m@Wx + bx via MFMA (N=4 real cols)
            {
                bf16_8 aw0 = *(const bf16_8*)(mst + n16*LDB + q*8);
                bf16_8 aw1 = *(const bf16_8*)(mst + n16*LDB + 32 + q*8);
                f32x4 acc = {0.f,0.f,0.f,0.f};
                acc = MFMA(aw0, wxf[0], acc);
                acc = MFMA(aw1, wxf[1], acc);
                if (n16 < 4) {
                    #pragma unroll
                    for (int r = 0; r < 4; ++r) {
                        int row = t*16 + q*4 + r;
                        if (row < NEDGE) sWcB[row*4 + n16] = (__bf16)(acc[r] + bxv);
                    }
                }
            }
            // agg: lane = col; node index compile-time via full unroll
            {
                const int elim = (t == 8) ? 4 : 16;
                #pragma unroll
                for (int el = 0; el < 16; ++el) {
                    if (el < elim) {
                        const int node = (t*16 + el) / 11;
                        agg[node] += (float)mst[el*LDB + lane];
                    }
                }
            }
        }
        // agg -> sHb (Hb dead after edge loop); bf16 store loses nothing vs packA8 cast
        #pragma unroll
        for (int i = 0; i < NAG; ++i) sHb[i*LDB + lane] = (__bf16)agg[i];

        // ---- xacc (pre-update x reads) ----
        float xn[3];
        #pragma unroll
        for (int p = 0; p < 3; ++p) {
            int idx = p*64 + lane;
            float res = 0.f;
            if (idx < 144) {
                int xi = idx / 12, dv = idx % 12, v = dv & 3;
                float xiv = sx[xi*16 + dv];
                float acc = 0.f;
                #pragma unroll
                for (int j2 = 0; j2 < NAG; ++j2) {
                    int e = xi*11 + j2 - (j2 > xi ? 1 : 0);
                    e = (e < NEDGE) ? e : (NEDGE - 1);
                    float term = (xiv - sx[j2*16 + dv]) * (float)sWcB[e*4 + v];
                    acc += (j2 == xi) ? 0.f : term;
                }
                res = xiv + acc * (1.0f / 11.0f);
            }
            xn[p] = res;
        }
        // ---- Wh1: t1 = silu([h,agg]@Wh1 + bh1) -> sHa (reuse) ----
        {
            bf16_8 ah0 = *(const bf16_8*)(sh  + rowA*LDB + q*8);
            bf16_8 ah1 = *(const bf16_8*)(sh  + rowA*LDB + 32 + q*8);
            bf16_8 ag0 = *(const bf16_8*)(sHb + rowA*LDB + q*8);
            bf16_8 ag1 = *(const bf16_8*)(sHb + rowA*LDB + 32 + q*8);
            #pragma unroll
            for (int nt = 0; nt < 4; ++nt) {
                f32x4 acc = {0.f,0.f,0.f,0.f};
                acc = MFMA(ah0, frg<WS>(wsb, L+24+nt*4+0, Wh1l, 0,  nt*16+n16, lane), acc);
                acc = MFMA(ah1, frg<WS>(wsb, L+24+nt*4+1, Wh1l, 32, nt*16+n16, lane), acc);
                acc = MFMA(ag0, frg<WS>(wsb, L+24+nt*4+2, Wh1l, 64, nt*16+n16, lane), acc);
                acc = MFMA(ag1, frg<WS>(wsb, L+24+nt*4+3, Wh1l, 96, nt*16+n16, lane), acc);
                #pragma unroll
                for (int r = 0; r < 4; ++r) {
                    int row = q*4 + r;
                    if (row < NAG) sHa[row*LDB + nt*16+n16] = (__bf16)silu_f(acc[r] + bh1v[nt]);
                }
            }
        }
        // ---- x writeback; Wh2: h += t1@Wh2 + bh2 (register residual) ----
        #pragma unroll
        for (int p = 0; p < 3; ++p) {
            int idx = p*64 + lane;
            if (idx < 144) sx[(idx/12)*16 + idx%12] = xn[p];
        }
        {
            bf16_8 at0 = *(const bf16_8*)(sHa + rowA*LDB + q*8);
            bf16_8 at1 = *(const bf16_8*)(sHa + rowA*LDB + 32 + q*8);
            #pragma unroll
            for (int nt = 0; nt < 4; ++nt) {
                f32x4 acc = {0.f,0.f,0.f,0.f};
                acc = MFMA(at0, frg<WS>(wsb, L+40+nt*2+0, Wh2l, 0,  nt*16+n16, lane), acc);
                acc = MFMA(at1, frg<WS>(wsb, L+40+nt*2+1, Wh2l, 32, nt*16+n16, lane), acc);
                #pragma unroll
                for (int r = 0; r < 4; ++r) hC[nt][r] += acc[r] + bh2v[nt];
            }
            #pragma unroll
            for (int nt = 0; nt < 4; ++nt)
                #pragma unroll
                for (int r = 0; r < 4; ++r) {
                    int row = q*4 + r;
                    if (row < NAG) sh[row*LDB + nt*16+n16] = (__bf16)hC[nt][r];
                }
        }
    }

    // ---- epilogue ----
    if (lane < NAG * 3) {
        int i = lane / 3, d = lane - i * 3;
        float mu = 0.f;
        #pragma unroll
        for (int v = 0; v < 4; ++v) mu += sx[i*16 + d*4 + v] * w_act[v];
        out[env * (NAG*3) + lane] = mu;
        out[NTH * NAG * 3 + env * (NAG*3) + lane] = -log_std[d] - 0.9189385332046727f;
    }
}

extern "C" void kernel_launch(void* const* d_in, const int* in_sizes, int n_in,
                              void* d_out, int out_size, void* d_ws, size_t ws_size,
                              hipStream_t stream) {
    // inputs: h0,x0,W_embed,b_embed,We1,be1,We2,be2,Wx,bx,Wh1,bh1,Wh2,bh2,w_act,log_std,row,col
    const float* h0   = (const float*)d_in[0];
    const float* x0   = (const float*)d_in[1];
    const float* Wem  = (const float*)d_in[2];
    const float* bem  = (const float*)d_in[3];
    const float* We1  = (const float*)d_in[4];
    const float* be1  = (const float*)d_in[5];
    const float* We2  = (const float*)d_in[6];
    const float* be2  = (const float*)d_in[7];
    const float* Wx   = (const float*)d_in[8];
    const float* bx   = (const float*)d_in[9];
    const float* Wh1  = (const float*)d_in[10];
    const float* bh1  = (const float*)d_in[11];
    const float* Wh2  = (const float*)d_in[12];
    const float* bh2  = (const float*)d_in[13];
    const float* wact = (const float*)d_in[14];
    const float* lstd = (const float*)d_in[15];
    float* out = (float*)d_out;

    if (ws_size >= (size_t)WS_BYTES) {
        prep_frags<<<dim3(WS_FRAGS), dim3(64), 0, stream>>>(Wem, We1, We2, Wh1, Wh2, (__bf16*)d_ws);
        egnn7<true><<<dim3(NTH), dim3(64), 0, stream>>>(
            h0, x0, Wem, bem, We1, be1, We2, be2, Wx, bx,
            Wh1, bh1, Wh2, bh2, wact, lstd, (const __bf16*)d_ws, out);
    } else {
        egnn7<false><<<dim3(NTH), dim3(64), 0, stream>>>(
            h0, x0, Wem, bem, We1, be1, We2, be2, Wx, bx,
            Wh1, bh1, Wh2, bh2, wact, lstd, nullptr, out);
    }
}